// Round 6
// baseline (14.048 us; speedup 1.0000x reference)
//
#include <hip/hip_runtime.h>

// MultiLabelEmbedding: mean-pooled embedding bag.
//  embed_table: float32 [100000, 32]   d_in[0]
//  indices:     int32   [16384, 50]    d_in[1]
//  lengths:     int32   [16384]        d_in[2]
//  out:         float32 [16384, 32]
//
// Round 6: round-5 structure + WAVE-UNIFORM SCALAR GUARD on gather steps.
//  Round 5 issued all 7 gather steps unconditionally (avg needed: 3.6) --
//  ~48% of gather instructions were clamped junk occupying TA/L1 slots.
//  len is wave-uniform -> `if (s*8 < len)` is a scalar branch (s_cbranch,
//  zero divergence); taken steps still issue back-to-back (independent).
//  Discriminator: TA-throughput-bound -> ~ -1.3us; latency-bound -> no change.

#define BAGS      16384
#define BAG_LEN   50
#define EMB_DIM   32
#define NSTEP     7        // ceil(50/8) element-groups of 8

__global__ __launch_bounds__(256) void multilabel_embed_kernel(
    const float* __restrict__ table,
    const int*   __restrict__ indices,
    const int*   __restrict__ lengths,
    float*       __restrict__ out)
{
    const int wavesPerBlock = blockDim.x >> 6;                    // 4
    int bag = blockIdx.x * wavesPerBlock + (threadIdx.x >> 6);
    bag = __builtin_amdgcn_readfirstlane(bag);                    // wave-uniform
    if (bag >= BAGS) return;

    const int lane = threadIdx.x & 63;
    const int sub  = (lane & 7) << 2;   // float offset within the 32-float row
    const int eg   = lane >> 3;         // element group 0..7

    int len = lengths[bag];
    len = __builtin_amdgcn_readfirstlane(len);                    // scalar
    if (len < 0) len = 0;
    if (len > BAG_LEN) len = BAG_LEN;

    // ONE coalesced load: all 50 bag indices into lane registers
    const int* __restrict__ idx = indices + bag * BAG_LEN;
    const int myidx = idx[(lane < BAG_LEN) ? lane : (BAG_LEN - 1)];

    // Phase 1: resolve per-step indices in-register (no memory loads)
    int  ix[NSTEP];
    bool valid[NSTEP];
#pragma unroll
    for (int s = 0; s < NSTEP; ++s) {
        const int l = s * 8 + eg;
        valid[s] = (l < len);
        const int cl = valid[s] ? l : 0;
        ix[s] = __shfl(myidx, cl);          // ds_bpermute, in-register
    }

    // Phase 2: issue gathers back-to-back, scalar-guarded per step.
    // Guard is wave-uniform (len is scalar) -> s_cbranch, no divergence.
    // r[s] for skipped steps stays 0 (and valid[s]=false anyway).
    float4 r[NSTEP];
#pragma unroll
    for (int s = 0; s < NSTEP; ++s) {
        r[s] = make_float4(0.f, 0.f, 0.f, 0.f);
        if (s * 8 < len) {
            r[s] = *reinterpret_cast<const float4*>(
                table + (size_t)ix[s] * EMB_DIM + sub);
        }
    }

    // Phase 3: predicated accumulate
    float4 acc = make_float4(0.f, 0.f, 0.f, 0.f);
#pragma unroll
    for (int s = 0; s < NSTEP; ++s) {
        acc.x += valid[s] ? r[s].x : 0.f;
        acc.y += valid[s] ? r[s].y : 0.f;
        acc.z += valid[s] ? r[s].z : 0.f;
        acc.w += valid[s] ? r[s].w : 0.f;
    }

    // reduce over element groups: lanes l, l^8, l^16, l^32 share `sub`
#pragma unroll
    for (int m = 8; m < 64; m <<= 1) {
        acc.x += __shfl_xor(acc.x, m);
        acc.y += __shfl_xor(acc.y, m);
        acc.z += __shfl_xor(acc.z, m);
        acc.w += __shfl_xor(acc.w, m);
    }

    if (eg == 0) {   // lanes 0..7 write the 128B output row
        const float inv = 1.0f / (float)(len > 0 ? len : 1);
        acc.x *= inv; acc.y *= inv; acc.z *= inv; acc.w *= inv;
        *reinterpret_cast<float4*>(out + (size_t)bag * EMB_DIM + sub) = acc;
    }
}

extern "C" void kernel_launch(void* const* d_in, const int* in_sizes, int n_in,
                              void* d_out, int out_size, void* d_ws, size_t ws_size,
                              hipStream_t stream) {
    const float* table   = (const float*)d_in[0];
    const int*   indices = (const int*)d_in[1];
    const int*   lengths = (const int*)d_in[2];
    float*       out     = (float*)d_out;

    const int threads = 256;                       // 4 waves = 4 bags per block
    const int grid = BAGS / 4;                     // 4096 blocks, 16384 waves

    multilabel_embed_kernel<<<grid, threads, 0, stream>>>(table, indices, lengths, out);
}

// Round 7
// 13.489 us; speedup vs baseline: 1.0415x; 1.0415x over previous
//
#include <hip/hip_runtime.h>

// MultiLabelEmbedding: mean-pooled embedding bag.
//  embed_table: float32 [100000, 32]   d_in[0]
//  indices:     int32   [16384, 50]    d_in[1]
//  lengths:     int32   [16384]        d_in[2]
//  out:         float32 [16384, 32]
//
// Round 7 = REVERT to round 5 (best: 13.48 us). Round 6's scalar guard
// regressed (+0.57 us): fewer gather instructions but ~same cache lines.
// Ceiling model (confirmed by rounds 2/3 identity, 5 win, 6 null/negative):
//   random 128B row-gathers, ~31% L2-hit, rest Infinity-Cache at ~700cy
//   loaded latency; per-CU miss tracking ~64 lines ->
//   256 CU x 64 x 128B / 292ns ~= 7.2 TB/s gather ceiling.
//   Round 5 moved 59.5 MB in ~8.2 us marginal = 7.3 TB/s  -> at ceiling.
//   Total floor ~= 8 us kernel + 5.3 us replay overhead ~= 13.3 us.
//
// Structure: one bag per wave; all 50 indices in ONE coalesced load;
// per-step index via __shfl (in-register); 7 independent dwordx4 gathers
// issued back-to-back; predicated accumulate; 3-level __shfl_xor reduce.

#define BAGS      16384
#define BAG_LEN   50
#define EMB_DIM   32
#define NSTEP     7        // ceil(50/8) element-groups of 8

__global__ __launch_bounds__(256) void multilabel_embed_kernel(
    const float* __restrict__ table,
    const int*   __restrict__ indices,
    const int*   __restrict__ lengths,
    float*       __restrict__ out)
{
    const int wavesPerBlock = blockDim.x >> 6;                    // 4
    int bag = blockIdx.x * wavesPerBlock + (threadIdx.x >> 6);
    bag = __builtin_amdgcn_readfirstlane(bag);                    // wave-uniform
    if (bag >= BAGS) return;

    const int lane = threadIdx.x & 63;
    const int sub  = (lane & 7) << 2;   // float offset within the 32-float row
    const int eg   = lane >> 3;         // element group 0..7

    int len = lengths[bag];
    len = __builtin_amdgcn_readfirstlane(len);                    // scalar
    if (len < 0) len = 0;
    if (len > BAG_LEN) len = BAG_LEN;

    // ONE coalesced load: all 50 bag indices into lane registers
    const int* __restrict__ idx = indices + bag * BAG_LEN;
    const int myidx = idx[(lane < BAG_LEN) ? lane : (BAG_LEN - 1)];

    // Phase 1: resolve per-step indices in-register (no memory loads)
    int  ix[NSTEP];
    bool valid[NSTEP];
#pragma unroll
    for (int s = 0; s < NSTEP; ++s) {
        const int l = s * 8 + eg;
        valid[s] = (l < len);
        const int cl = valid[s] ? l : 0;
        ix[s] = __shfl(myidx, cl);          // ds_bpermute, in-register
    }

    // Phase 2: issue ALL gathers back-to-back (7 independent dwordx4)
    float4 r[NSTEP];
#pragma unroll
    for (int s = 0; s < NSTEP; ++s) {
        r[s] = *reinterpret_cast<const float4*>(
            table + (size_t)ix[s] * EMB_DIM + sub);
    }

    // Phase 3: predicated accumulate
    float4 acc = make_float4(0.f, 0.f, 0.f, 0.f);
#pragma unroll
    for (int s = 0; s < NSTEP; ++s) {
        acc.x += valid[s] ? r[s].x : 0.f;
        acc.y += valid[s] ? r[s].y : 0.f;
        acc.z += valid[s] ? r[s].z : 0.f;
        acc.w += valid[s] ? r[s].w : 0.f;
    }

    // reduce over element groups: lanes l, l^8, l^16, l^32 share `sub`
#pragma unroll
    for (int m = 8; m < 64; m <<= 1) {
        acc.x += __shfl_xor(acc.x, m);
        acc.y += __shfl_xor(acc.y, m);
        acc.z += __shfl_xor(acc.z, m);
        acc.w += __shfl_xor(acc.w, m);
    }

    if (eg == 0) {   // lanes 0..7 write the 128B output row
        const float inv = 1.0f / (float)(len > 0 ? len : 1);
        acc.x *= inv; acc.y *= inv; acc.z *= inv; acc.w *= inv;
        *reinterpret_cast<float4*>(out + (size_t)bag * EMB_DIM + sub) = acc;
    }
}

extern "C" void kernel_launch(void* const* d_in, const int* in_sizes, int n_in,
                              void* d_out, int out_size, void* d_ws, size_t ws_size,
                              hipStream_t stream) {
    const float* table   = (const float*)d_in[0];
    const int*   indices = (const int*)d_in[1];
    const int*   lengths = (const int*)d_in[2];
    float*       out     = (float*)d_out;

    const int threads = 256;                       // 4 waves = 4 bags per block
    const int grid = BAGS / 4;                     // 4096 blocks, 16384 waves

    multilabel_embed_kernel<<<grid, threads, 0, stream>>>(table, indices, lengths, out);
}